// Round 3
// 103.631 us; speedup vs baseline: 1.0017x; 1.0017x over previous
//
#include <hip/hip_runtime.h>
#include <cstdint>
#include <cstddef>

typedef unsigned long long u64;
typedef unsigned int u32;
typedef unsigned short u16;

#define N_ 4096
#define SROW_ 48     // u16 stride per succ row: [0]=count, [1..47]=succ indices

__device__ __forceinline__ float sigf(float x) { return 1.0f / (1.0f + expf(-x)); }

// ---------------- ball adjacency from LDS halo tile (logic verified R6-R10) ---
// Geometric pruning (offsets in open (0,1)):
//   cut=1.0 : two axes at |dcell|=2 give min d2 >= 1.17 > 1.0  -> 80-cell ball
//   cut=0.75: any axis at |dcell|=2 exceeds 0.75 strictly      -> 26-cell ball
// "earlier(j,i)": okey_j > okey_i || (okey_j==okey_i && n_j < n_i)
// == "j earlier in ref's stable desc-conf sort" (key orientation, label-free).
// Returns pred count (earlier conflictors); writes succ list (later ones):
// rowp[0]=count, rowp[1..] = succ anchor indices.
template <int EXT>
__device__ __forceinline__ int build_adj(
    const float4* __restrict__ hp, float4 self, int d0, int hl, int wl, int n,
    float cut2, u16* __restrict__ rowp) {
  u32 okey = __float_as_uint(self.w);
  int pcnt = 0, scnt = 0;
  #pragma unroll
  for (int dd = -EXT; dd <= EXT; ++dd) {
    #pragma unroll
    for (int dh = -EXT; dh <= EXT; ++dh) {
      #pragma unroll
      for (int dw = -EXT; dw <= EXT; ++dw) {
        if (dd == 0 && dh == 0 && dw == 0) continue;
        if ((dd * dd == 4) + (dh * dh == 4) + (dw * dw == 4) > 1) continue;
        int d2 = d0 + dd;
        if ((u32)d2 >= 4u) continue;           // d has no halo; h/w halo'd in LDS
        float4 pn = hp[d2 * 144 + (hl + dh) * 12 + (wl + dw)];  // dead -> 1e9
        float dx = pn.x - self.x, dy = pn.y - self.y, dz = pn.z - self.z;
        float dsq = dx * dx + dy * dy + dz * dz;
        if (dsq < cut2) {                      // conflict (pn alive by 1e9 filter)
          u32 ok2 = __float_as_uint(pn.w);
          int n2 = n + (dd << 10) + (dh << 5) + dw;  // valid since pn alive
          bool earlier = (ok2 > okey) || (ok2 == okey && n2 < n);
          if (earlier) {
            pcnt++;                            // predecessor: count only
          } else {
            if (scnt < SROW_ - 1) rowp[1 + scnt] = (u16)n2;  // successor: record
            scnt++;
          }
        }
      }
    }
  }
  rowp[0] = (u16)(scnt < SROW_ ? scnt : SROW_ - 1);
  return pcnt;
}

// ---------------- K1: fused compact+adjacency, tile+halo ----------------------
// 16 blocks per pair; block owns a 4(d)x8x8 anchor tile. Computes the 4x12x12
// halo region (conf/argmax/okey/sigmoid-pos) into LDS (2.25x redundant compute,
// no inter-block dependency), then per interior anchor writes dense posG
// (w=okey, dead=1e9), pred COUNT (pdeg, -1 = not a candidate) and succ LIST.
__global__ __launch_bounds__(256) void k_build(
    const float* __restrict__ pc, const float* __restrict__ pb,
    float4* __restrict__ posG, int* __restrict__ pdeg, u16* __restrict__ succL) {
  int blk = blockIdx.x;
  int pair = blk >> 4, tile = blk & 15;
  int b = pair >> 1, c = (pair & 1) + 1;
  int th0 = ((tile >> 2) << 3);   // 0,8,16,24
  int tw0 = ((tile & 3) << 3);
  __shared__ float4 hpos[576];    // 4 x 12 x 12 halo region
  const float* pcb = pc + (size_t)b * 3 * N_;
  const float* pbb = pb + (size_t)b * 3 * N_;
  for (int e = threadIdx.x; e < 576; e += 256) {
    int d = e / 144, rem = e - d * 144;
    int hh = rem / 12, ww = rem - hh * 12;
    int h = th0 + hh - 2, w = tw0 + ww - 2;
    float4 v; v.x = 1e9f; v.y = 1e9f; v.z = 1e9f; v.w = 0.f;
    if ((u32)h < 32u && (u32)w < 32u) {
      int n = (d << 10) | (h << 5) | w;
      float v0 = pcb[n], v1 = pcb[n + N_], v2 = pcb[n + 2 * N_];
      float cf = v0; int a = 0;
      if (v1 > cf) { cf = v1; a = 1; }
      if (v2 > cf) { cf = v2; a = 2; }
      if (a == c) {
        u32 o = __float_as_uint(cf);
        o ^= (o >> 31) ? 0xFFFFFFFFu : 0x80000000u;   // ascending-orderable conf
        // (g+s)/dims*REAL == (g+s)*{0.75,0.78125,0.78125} bit-exact (pow2 dims)
        v.x = ((float)d + sigf(pbb[n])) * 0.75f;
        v.y = ((float)h + sigf(pbb[n + N_])) * 0.78125f;
        v.z = ((float)w + sigf(pbb[n + 2 * N_])) * 0.78125f;
        v.w = __uint_as_float(o);
      }
    }
    hpos[e] = v;
  }
  __syncthreads();
  // interior pass: one thread per anchor of the tile
  int tid = threadIdx.x;
  int d0 = tid >> 6;              // 0..3
  int hl = ((tid >> 3) & 7) + 2;  // 2..9 (local, halo offset)
  int wl = (tid & 7) + 2;
  int n = (d0 << 10) | ((th0 + hl - 2) << 5) | (tw0 + wl - 2);
  float4 self = hpos[d0 * 144 + hl * 12 + wl];
  int row = pair * N_ + n;
  posG[row] = self;
  int pd = -1;                    // -1 = not a candidate of class c
  if (self.x < 1e8f) {
    u16* rowp = succL + (size_t)row * SROW_;
    if (pair & 1) pd = build_adj<1>(hpos, self, d0, hl, wl, n, 0.5625f, rowp);
    else          pd = build_adj<2>(hpos, self, d0, hl, wl, n, 1.0f, rowp);
  }
  pdeg[row] = pd;
}

// ---------------- K2: event-driven NMS fixpoint -------------------------------
// Exact ref semantics per iteration (both stages use the previous iteration's
// alive snapshot):
//   free_i  = alive_i && (# alive preds == 0)
//   alive'_j = alive_j && no free pred
// Implemented with alive-pred COUNTERS + one-shot pushes:
//   stage0: node discovering its own death pushes cnt-- to its successors
//   stage1: newly-free node pushes kills (aliveB=0) to its successors
// Deaths/frees happen once per node => per-iteration cost is O(N) coalesced
// LDS reads + 2 barriers; scattered work totals O(E) over the whole run.
// free && killed same iter impossible (free => all preds dead => no free pred),
// so frees are permanent and the snapshot discipline is exact.
// Early break when an iteration yields no new frees (=> no kills => static).
// Epilogue dead-marks posG.x in place (k_match consumes posG directly).
__global__ __launch_bounds__(1024) void k_nms(
    const int* __restrict__ pdeg, const u16* __restrict__ succL,
    float4* __restrict__ posG, int* __restrict__ out) {
  int pair = blockIdx.x, tid = threadIdx.x;
  __shared__ unsigned char aliveB[4096];
  __shared__ int cntA[4096];      // # still-alive predecessors
  __shared__ int flag[2], acnt;
  bool al[4], fre[4], wasC[4];
  #pragma unroll
  for (int q = 0; q < 4; ++q) {
    int r = tid + (q << 10);
    int pd = pdeg[(pair << 12) + r];
    al[q] = (pd >= 0); fre[q] = false; wasC[q] = (pd >= 0);
    aliveB[r] = al[q] ? 1 : 0;
    cntA[r] = pd > 0 ? pd : 0;
  }
  if (tid == 0) { flag[0] = 0; flag[1] = 0; acnt = 0; }
  __syncthreads();

  for (int iter = 0; iter < 32; ++iter) {
    // ---- stage 0: discover own death (from prev-iter kills), push cnt--
    #pragma unroll
    for (int q = 0; q < 4; ++q) {
      int r = tid + (q << 10);
      if (al[q] && !fre[q]) {
        if (!aliveB[r]) {                       // killed in a prior iteration
          al[q] = false;
          const u16* rp = succL + (size_t)((pair << 12) + r) * SROW_;
          int sc = rp[0];
          for (int k = 1; k <= sc; ++k) atomicSub(&cntA[rp[k]], 1);
        }
      }
    }
    __syncthreads();                            // cnt-- visible before free check
    // ---- stage 1: newly-free nodes push kills to successors
    int lch = 0;
    #pragma unroll
    for (int q = 0; q < 4; ++q) {
      int r = tid + (q << 10);
      if (al[q] && !fre[q] && cntA[r] == 0) {
        fre[q] = true; lch = 1;
        const u16* rp = succL + (size_t)((pair << 12) + r) * SROW_;
        int sc = rp[0];
        for (int k = 1; k <= sc; ++k) aliveB[rp[k]] = 0;
      }
    }
    if (tid == 0) flag[(iter + 1) & 1] = 0;     // reset NEXT flag (pre-barrier:
    if (lch) flag[iter & 1] = 1;                //  race-free vs next iter's read)
    __syncthreads();                            // kills + flag visible
    if (!flag[iter & 1]) break;                 // no new frees => fixpoint exact
  }

  // epilogue: aliveB is ground truth (al[] may lag final-iteration kills)
  #pragma unroll
  for (int q = 0; q < 4; ++q) {
    int r = tid + (q << 10);
    int a = aliveB[r];
    if (!a && wasC[q]) posG[(pair << 12) + r].x = 1e9f;  // dead-mark in place
    u64 ball = __ballot(a != 0);
    if ((tid & 63) == 0 && ball) atomicAdd(&acnt, __popcll(ball));
  }
  __syncthreads();
  if (tid == 0) {
    out[pair * 3 + 0] = 0;        // tp  (K3 adds)
    out[pair * 3 + 1] = acnt;     // fp = A - tp (K3 subtracts)
    out[pair * 3 + 2] = 0;        // fn = t_cls - tp (K3 adds/subtracts)
  }
}

// ---------------- K3: lattice-ball target matching (verified R8/R10) ----------
// One thread per anchor; a matching alive pred lies within the same +/-2 ball
// (target offset in [0,1), pred offset in (0,1)); includes the center cell.
// Reads posG directly: dead/killed rows have x=1e9 -> dist rejects.
template <int EXT>
__device__ __forceinline__ int match_ball(
    const float4* __restrict__ alive, int n, float tx, float ty, float tz,
    float cut2) {
  int d0 = n >> 10, h0 = (n >> 5) & 31, w0 = n & 31;
  int m = 0;
  #pragma unroll
  for (int dd = -EXT; dd <= EXT; ++dd) {
    #pragma unroll
    for (int dh = -EXT; dh <= EXT; ++dh) {
      #pragma unroll
      for (int dw = -EXT; dw <= EXT; ++dw) {
        if ((dd * dd == 4) + (dh * dh == 4) + (dw * dw == 4) > 1) continue;
        int d2i = d0 + dd, h2i = h0 + dh, w2i = w0 + dw;
        if ((u32)d2i < 4u && (u32)h2i < 32u && (u32)w2i < 32u) {
          int n2 = (d2i << 10) | (h2i << 5) | w2i;
          float4 p = alive[n2];               // dead -> 1e9 -> dist rejects
          float dx = p.x - tx, dy = p.y - ty, dz = p.z - tz;
          m |= (int)(dx * dx + dy * dy + dz * dz < cut2);
        }
      }
    }
  }
  return m;
}

__global__ __launch_bounds__(256) void k_match(
    const float4* __restrict__ posG,
    const int* __restrict__ tcls, const float* __restrict__ tb,
    int* __restrict__ out) {
  int idx = blockIdx.x * 256 + threadIdx.x;   // 0..16383
  int pair = idx >> 12, n = idx & (N_ - 1);
  int b = pair >> 1, c = (pair & 1) + 1;
  float cut2 = (pair & 1) ? 0.5625f : 1.0f;
  __shared__ int s_tp, s_t;
  if (threadIdx.x == 0) { s_tp = 0; s_t = 0; }
  __syncthreads();
  int isC = (tcls[b * N_ + n] == c) ? 1 : 0;
  float d = (float)(n >> 10), h = (float)((n >> 5) & 31), w = (float)(n & 31);
  const float* tbp = tb + ((size_t)b * N_ + n) * 3;
  float tx = (d + tbp[0]) * 0.75f;
  float ty = (h + tbp[1]) * 0.78125f;
  float tz = (w + tbp[2]) * 0.78125f;
  const float4* alive = posG + (size_t)pair * N_;
  int m;
  if (pair & 1) m = match_ball<1>(alive, n, tx, ty, tz, cut2);
  else          m = match_ball<2>(alive, n, tx, ty, tz, cut2);
  m &= isC;
  atomicAdd(&s_tp, m);
  atomicAdd(&s_t, isC);
  __syncthreads();
  if (threadIdx.x == 0) {
    atomicAdd(&out[pair * 3 + 0], s_tp);
    atomicAdd(&out[pair * 3 + 1], -s_tp);
    atomicAdd(&out[pair * 3 + 2], s_t - s_tp);
  }
}

// ------------------------------------------------------------------------------
extern "C" void kernel_launch(void* const* d_in, const int* in_sizes, int n_in,
                              void* d_out, int out_size, void* d_ws, size_t ws_size,
                              hipStream_t stream) {
  (void)in_sizes; (void)n_in; (void)out_size; (void)ws_size;
  const float* pc = (const float*)d_in[0];  // pred_clses (B,3,4,32,32) f32
  const float* pb = (const float*)d_in[1];  // pred_boxes (B,3,4,32,32) f32
  const int*   tc = (const int*)d_in[2];    // targ_clses (B,4,32,32) i32
  const float* tb = (const float*)d_in[3];  // targ_boxes (B,4,32,32,3) f32
  int* out = (int*)d_out;                   // (B, C-1, 1, 3) int32 counts

  char* ws = (char*)d_ws;
  size_t off = 0;
  auto alloc = [&](size_t bytes) -> void* {
    void* p = ws + off;
    off += (bytes + 255) & ~(size_t)255;
    return p;
  };
  float4* posG  = (float4*)alloc((size_t)4 * N_ * 16);
  int*    pdeg  = (int*)alloc((size_t)4 * N_ * 4);
  u16*    succL = (u16*)alloc((size_t)4 * N_ * SROW_ * 2);

  k_build<<<64, 256, 0, stream>>>(pc, pb, posG, pdeg, succL);
  k_nms<<<4, 1024, 0, stream>>>(pdeg, succL, posG, out);
  k_match<<<64, 256, 0, stream>>>(posG, tc, tb, out);
}